// Round 5
// baseline (247.148 us; speedup 1.0000x reference)
//
#include <hip/hip_runtime.h>
#include <math.h>

#define Bn 8
#define Sn 2048
#define Dn 256
#define Hn 4
#define DHn 64
#define Mn (Bn*Sn)   // 16384 rows

typedef short bf16x8 __attribute__((ext_vector_type(8)));
typedef float f32x2  __attribute__((ext_vector_type(2)));
typedef float f32x4  __attribute__((ext_vector_type(4)));
typedef float f32x16 __attribute__((ext_vector_type(16)));
typedef int   i32x4  __attribute__((ext_vector_type(4)));
typedef unsigned short u16;
typedef unsigned int   u32;
typedef unsigned long long u64;

#if defined(__has_builtin)
#if __has_builtin(__builtin_amdgcn_global_load_lds)
#define HAVE_GLL 1
#endif
#if __has_builtin(__builtin_amdgcn_permlane32_swap)
#define HAVE_PLS 1
#endif
#endif
#ifndef HAVE_GLL
#define HAVE_GLL 0
#endif
#ifndef HAVE_PLS
#define HAVE_PLS 0
#endif

// ---------------------------------------------------------------------------
// helpers
// ---------------------------------------------------------------------------
__device__ __forceinline__ u16 f2b(float f){
    u32 u = __float_as_uint(f);
    u32 r = (u + 0x7fffu + ((u >> 16) & 1u)) >> 16;
    return (u16)r;
}
__device__ __forceinline__ float b2f(u16 h){ return __uint_as_float(((u32)h) << 16); }
__device__ __forceinline__ u32 cvtpk(float lo, float hi){
    u32 r;
    asm("v_cvt_pk_bf16_f32 %0, %1, %2" : "=v"(r) : "v"(lo), "v"(hi));
    return r;
}

// gelu(x) = x - x / (exp2(K1*x + K2*x^3) + 1)   [tanh form, exp2 domain]
__device__ __forceinline__ float gelu_f(float x){
    const float K1 = 2.3021143113f;      // 2*log2(e)*sqrt(2/pi)
    const float K2 = 0.1029390163f;      // K1 * 0.044715
    float x2 = x * x;
    float arg = fmaf(x2 * x, K2, x * K1);
    float e = exp2f(arg);
    float r = __builtin_amdgcn_rcpf(e + 1.0f);
    return x - x * r;
}

// ---------------------------------------------------------------------------
// prep: input cvt (blocks 0..6143) + weight convert/transpose (rest)
// ---------------------------------------------------------------------------
struct WtArgs {
    const float* src[13];
    int kdim[13], ndim[13], dstoff[13], t0[13];
};

__global__ __launch_bounds__(256) void prep_k(const float* __restrict__ lf, const float* __restrict__ gf,
                                              const float* __restrict__ tf,
                                              u16* __restrict__ o0, u16* __restrict__ o1, u16* __restrict__ o2,
                                              WtArgs a, u16* __restrict__ dst)
{
    __shared__ float tile[32][33];
    int bx = blockIdx.x;
    if (bx < 6144){
        int part = bx >> 11, blk = bx & 2047;
        const float* s = (part == 0) ? lf : (part == 1) ? gf : tf;
        u16* d = (part == 0) ? o0 : (part == 1) ? o1 : o2;
        size_t base = ((size_t)blk * 256 + threadIdx.x) * 8;
        float4 v0 = *(const float4*)(s + base);
        float4 v1 = *(const float4*)(s + base + 4);
        i32x4 o;
        o[0] = (int)cvtpk(v0.x, v0.y); o[1] = (int)cvtpk(v0.z, v0.w);
        o[2] = (int)cvtpk(v1.x, v1.y); o[3] = (int)cvtpk(v1.z, v1.w);
        *(i32x4*)(d + base) = o;
        return;
    }
    int tb = bx - 6144;
    int wi = 0;
    #pragma unroll
    for (int i = 1; i < 13; ++i) if (tb >= a.t0[i]) wi = i;
    int tt = tb - a.t0[wi];
    int N = a.ndim[wi], K = a.kdim[wi];
    int ntn = N >> 5;
    int tn = tt % ntn, tk = tt / ntn;
    int n0 = tn * 32, k0 = tk * 32;
    const float* src = a.src[wi];
    int r = threadIdx.x >> 5, c = threadIdx.x & 31;
    #pragma unroll
    for (int rr = 0; rr < 4; ++rr)
        tile[r*4+rr][c] = src[(size_t)(k0 + r*4 + rr) * N + n0 + c];
    __syncthreads();
    u16* out = dst + a.dstoff[wi];
    #pragma unroll
    for (int rr = 0; rr < 4; ++rr)
        out[(size_t)(n0 + r*4 + rr) * K + k0 + c] = f2b(tile[c][r*4+rr]);
}

// ---------------------------------------------------------------------------
// GEMM (grouped): C = act((A @ W + bias) * scale). A bf16 [M,K], Wt bf16 [N,K].
// 64x128 tile, BK=32, 4 waves, 2-phase dbuf LDS, counted vmcnt(3), GLL w16.
// XCD-chunked block swizzle (gy must be 256, gx pow2, total%8==0).
// ---------------------------------------------------------------------------
struct Grp {
    const u16* A[5];
    const u16* Wt[5];
    const float* bias[5];
    void* C[5];
    float scale[5];
};

template<int ACT, int OUTF32>
__global__ __launch_bounds__(256, 4) void gemm_k(Grp g, int N, int K)
{
    // ---- XCD-aware bijective swizzle: each XCD gets a contiguous logical chunk
    const u32 gx = gridDim.x;
    const u32 lgx = (u32)__builtin_ctz(gx);
    const u32 total = gx * gridDim.y * gridDim.z;
    const u32 lid = (blockIdx.z * gridDim.y + blockIdx.y) * gx + blockIdx.x;
    const u32 nl = (lid & 7) * (total >> 3) + (lid >> 3);
    const u32 bz = nl >> (lgx + 8);
    const u32 r2 = nl & ((1u << (lgx + 8)) - 1u);
    const u32 by = r2 >> lgx;
    const u32 bx = r2 & ((1u << lgx) - 1u);

    const u16* __restrict__ A   = g.A[bz];
    const u16* __restrict__ Wt  = g.Wt[bz];
    const float* __restrict__ bias = g.bias[bz];
    void* __restrict__ Cv = g.C[bz];
    const float scale = g.scale[bz];

    __shared__ u16 sm[2][6144];           // per buf: A tile [64][32] @0, B tile [128][32] @2048
    const int tid = threadIdx.x;
    const int w = tid >> 6, lane = tid & 63;
    const int l15 = lane & 15, l4 = lane >> 4;
    const int wr = w & 1, wc = w >> 1;
    const int bm = by << 6, bn = bx << 7;
    const int xq = l4 ^ ((lane >> 1) & 3);    // read-side swizzle

    f32x4 acc[4][2];
    #pragma unroll
    for (int nf = 0; nf < 4; ++nf)
        #pragma unroll
        for (int mf = 0; mf < 2; ++mf){
            acc[nf][mf][0]=0.f; acc[nf][mf][1]=0.f; acc[nf][mf][2]=0.f; acc[nf][mf][3]=0.f;
        }

    auto STAGE = [&](int buf, int kt){
        #pragma unroll
        for (int j = 0; j < 3; ++j){
            int ch = w*192 + j*64 + lane;     // chunk 0..767 (16B units)
            int isB = ch >= 256;
            int cc  = isB ? ch - 256 : ch;
            int row = cc >> 2, q = cc & 3;
            int qs  = q ^ ((row >> 1) & 3);   // source pre-swizzle
            const u16* src = isB ? (Wt + (size_t)(bn + row) * K + kt + qs*8)
                                 : (A  + (size_t)(bm + row) * K + kt + qs*8);
#if HAVE_GLL
            u16* lb = &sm[buf][(size_t)(w*192 + j*64) * 8];
            __builtin_amdgcn_global_load_lds((const __attribute__((address_space(1))) void*)src,
                                             (__attribute__((address_space(3))) void*)lb, 16, 0, 0);
#else
            *(i32x4*)&sm[buf][(size_t)ch * 8] = *(const i32x4*)src;
#endif
        }
    };

    STAGE(0, 0);
    const int nk = K >> 5;
    for (int t = 0; t < nk; ++t){
        const int cur = t & 1;
        if (t + 1 < nk){
            STAGE(cur ^ 1, (t + 1) << 5);
#if HAVE_GLL
            asm volatile("s_waitcnt vmcnt(3)" ::: "memory");
#endif
        } else {
#if HAVE_GLL
            asm volatile("s_waitcnt vmcnt(0)" ::: "memory");
#endif
        }
        __builtin_amdgcn_s_barrier();
        asm volatile("" ::: "memory");

        const u16* As = sm[cur];
        const u16* Bs = sm[cur] + 2048;
        bf16x8 wf[4], af[2];
        #pragma unroll
        for (int nf = 0; nf < 4; ++nf)
            wf[nf] = *(const bf16x8*)(Bs + (size_t)(wc*64 + nf*16 + l15) * 32 + xq*8);
        #pragma unroll
        for (int mf = 0; mf < 2; ++mf)
            af[mf] = *(const bf16x8*)(As + (size_t)(wr*32 + mf*16 + l15) * 32 + xq*8);
        __builtin_amdgcn_s_setprio(1);
        #pragma unroll
        for (int nf = 0; nf < 4; ++nf)
            #pragma unroll
            for (int mf = 0; mf < 2; ++mf)
                acc[nf][mf] = __builtin_amdgcn_mfma_f32_16x16x32_bf16(wf[nf], af[mf], acc[nf][mf], 0, 0, 0);
        __builtin_amdgcn_s_setprio(0);

        asm volatile("" ::: "memory");
        __builtin_amdgcn_s_barrier();
    }

    // epilogue: D[n][m]: n = bn + wc*64 + nf*16 + l4*4 + r, m = bm + wr*32 + mf*16 + l15
    #pragma unroll
    for (int nf = 0; nf < 4; ++nf){
        const int n0 = bn + wc*64 + nf*16 + l4*4;
        float4 b4 = *(const float4*)(bias + n0);
        #pragma unroll
        for (int mf = 0; mf < 2; ++mf){
            const int m = bm + wr*32 + mf*16 + l15;
            float r0 = (acc[nf][mf][0] + b4.x) * scale;
            float r1 = (acc[nf][mf][1] + b4.y) * scale;
            float r2 = (acc[nf][mf][2] + b4.z) * scale;
            float r3 = (acc[nf][mf][3] + b4.w) * scale;
            if (ACT){ r0 = gelu_f(r0); r1 = gelu_f(r1); r2 = gelu_f(r2); r3 = gelu_f(r3); }
            if (OUTF32){
                float4 o; o.x = r0; o.y = r1; o.z = r2; o.w = r3;
                *(float4*)((float*)Cv + (size_t)m * N + n0) = o;
            } else {
                u64 p = (u64)cvtpk(r0, r1) | ((u64)cvtpk(r2, r3) << 32);
                *(u64*)((u16*)Cv + (size_t)m * N + n0) = p;
            }
        }
    }
}

// ---------------------------------------------------------------------------
// bf16 MFMA flash attention, double-buffered K/V LDS (one barrier per tile).
// Q pre-scaled by log2(e)/8 in producer GEMM; fixed m=0 softmax (exact here).
// K staged via global_load_lds into LINEAR LDS with involution chunk-XOR
// (source-side pre-swizzle + same XOR on read, rule #21). V reg-staged with
// byte-perm transpose into padded V^T. XCD-chunked 1D block swizzle.
// ---------------------------------------------------------------------------
#define PSEL(idx, mm) ((((idx) >> 2) == 0) ? pp0[(4*((idx)&3)+(mm))>>1][(4*((idx)&3)+(mm))&1] \
                                           : pp1[(4*((idx)&3)+(mm))>>1][(4*((idx)&3)+(mm))&1])

template<int FUSE>
__global__ __launch_bounds__(256, 2) void attn_k(const u16* __restrict__ Q, const u16* __restrict__ Kp,
                                                 const u16* __restrict__ Vp, u16* __restrict__ O,
                                                 const u16* __restrict__ ADD)
{
    __shared__ u16 Kl[2][4096];          // [buf][chunk-slot*8], linear (GLL dest)
    __shared__ u16 Vt[2][4608];          // [buf][d*72 + k], padded

    const int tid = threadIdx.x;
    const int w = tid >> 6, lane = tid & 63;
    const int c31 = lane & 31, h = lane >> 5;

    // ---- XCD-chunked swizzle: 512 blocks, xcd gets 4 heads x 16 q-blocks
    const int lid = blockIdx.x;
    const int nl = (lid & 7) * 64 + (lid >> 3);
    const int bh = nl >> 4;                          // b*H + h
    const int qb = (nl & 15) << 7;
    const size_t hb = (size_t)(bh >> 2) * Sn * Dn + (size_t)(bh & 3) * DHn;
    const int qrow = qb + w*32 + c31;

    bf16x8 qf[4];
    #pragma unroll
    for (int kc = 0; kc < 4; ++kc)
        qf[kc] = *(const bf16x8*)(Q + hb + (size_t)qrow * Dn + kc*16 + h*8);

    f32x16 ot0, ot1;
    #pragma unroll
    for (int r = 0; r < 16; ++r){ ot0[r] = 0.f; ot1[r] = 0.f; }
    float ll = 0.f;

    // loop-invariant LDS read offsets (u16 units)
    const int kx = c31 & 7;
    int koff0[4], koff1[4], voff0[4], voff1[4];
    #pragma unroll
    for (int kc = 0; kc < 4; ++kc){
        int q = 2*kc + h;
        koff0[kc] = c31*64        + (q ^ kx)*8;
        koff1[kc] = (32 + c31)*64 + (q ^ kx)*8;
        voff0[kc] = c31*72        + kc*16 + h*8;
        voff1[kc] = (32 + c31)*72 + kc*16 + h*8;
    }

    const int vk0 = (tid & 15) * 4, vd0 = (tid >> 4) * 4; // V^T: 4x4 block/thread
    const u32 SEL_LO = 0x05040100u, SEL_HI = 0x07060302u;

    u64 v0, v1, v2, v3;
    auto LOADV = [&](int kt2){
        const u16* vb = Vp + hb + (size_t)(kt2 + vk0) * Dn + vd0;
        v0 = *(const u64*)(vb);
        v1 = *(const u64*)(vb + Dn);
        v2 = *(const u64*)(vb + 2*Dn);
        v3 = *(const u64*)(vb + 3*Dn);
    };
    auto GLLK = [&](int buf, int kt2){
        #pragma unroll
        for (int j = 0; j < 2; ++j){
            int ch = w*128 + j*64 + lane;            // chunk slot 0..511
            int r = ch >> 3, q = ch & 7;
            int qs = q ^ (r & 7);                    // involution source swizzle
            const u16* src = Kp + hb + (size_t)(kt2 + r) * Dn + qs*8;
#if HAVE_GLL
            u16* lb = &Kl[buf][(size_t)(w*128 + j*64) * 8];
            __builtin_amdgcn_global_load_lds((const __attribute__((address_space(1))) void*)src,
                                             (__attribute__((address_space(3))) void*)lb, 16, 0, 0);
#else
            *(i32x4*)&Kl[buf][(size_t)ch * 8] = *(const i32x4*)src;
#endif
        }
    };
    auto WRITEV = [&](int buf){
        u32 a0 = (u32)v0, a1 = (u32)v1, a2 = (u32)v2, a3 = (u32)v3;
        u32 b0 = (u32)(v0 >> 32), b1 = (u32)(v1 >> 32), b2 = (u32)(v2 >> 32), b3 = (u32)(v3 >> 32);
        u64 wd0 = (u64)__builtin_amdgcn_perm(a1, a0, SEL_LO) | ((u64)__builtin_amdgcn_perm(a3, a2, SEL_LO) << 32);
        u64 wd1 = (u64)__builtin_amdgcn_perm(a1, a0, SEL_HI) | ((u64)__builtin_amdgcn_perm(a3, a2, SEL_HI) << 32);
        u64 wd2 = (u64)__builtin_amdgcn_perm(b1, b0, SEL_LO) | ((u64)__builtin_amdgcn_perm(b3, b2, SEL_LO) << 32);
        u64 wd3 = (u64)__builtin_amdgcn_perm(b1, b0, SEL_HI) | ((u64)__builtin_amdgcn_perm(b3, b2, SEL_HI) << 32);
        *(u64*)&Vt[buf][(size_t)(vd0 + 0)*72 + vk0] = wd0;
        *(u64*)&Vt[buf][(size_t)(vd0 + 1)*72 + vk0] = wd1;
        *(u64*)&Vt[buf][(size_t)(vd0 + 2)*72 + vk0] = wd2;
        *(u64*)&Vt[buf][(size_t)(vd0 + 3)*72 + vk0] = wd3;
    };

    // prologue: stage tile 0 into buf 0
    LOADV(0);
    GLLK(0, 0);
    WRITEV(0);
    __syncthreads();          // drains vmcnt (GLL) + lgkm (ds_write)

    #pragma unroll 2
    for (int t = 0; t < 32; ++t){
        const int c = t & 1;
        const bool more = (t < 31);
        if (more){
            LOADV((t + 1) << 6);       // V regs first (consumed pre-barrier)
            GLLK(c ^ 1, (t + 1) << 6); // K direct-to-LDS (drained by barrier)
        }

        // --- S^T = K @ Q^T  (per lane: 32 pre-scaled scores for q = c31)
        f32x16 s0, s1;
        #pragma unroll
        for (int r = 0; r < 16; ++r){ s0[r] = 0.f; s1[r] = 0.f; }
        __builtin_amdgcn_s_setprio(1);
        #pragma unroll
        for (int kc = 0; kc < 4; ++kc){
            bf16x8 k0 = *(const bf16x8*)&Kl[c][koff0[kc]];
            bf16x8 k1 = *(const bf16x8*)&Kl[c][koff1[kc]];
            s0 = __builtin_amdgcn_mfma_f32_32x32x16_bf16(k0, qf[kc], s0, 0, 0, 0);
            s1 = __builtin_amdgcn_mfma_f32_32x32x16_bf16(k1, qf[kc], s1, 0, 0, 0);
        }
        __builtin_amdgcn_s_setprio(0);

        // --- softmax numerator, fixed m=0: p = exp2(s); packed-pair sums
        f32x2 pp0[8], pp1[8];
        f32x2 rv = {0.f, 0.f};
        #pragma unroll
        for (int r = 0; r < 8; ++r){
            pp0[r][0] = exp2f(s0[2*r]); pp0[r][1] = exp2f(s0[2*r+1]);
            pp1[r][0] = exp2f(s1[2*r]); pp1[r][1] = exp2f(s1[2*r+1]);
            rv += pp0[r];
            rv += pp1[r];
        }
        ll += rv[0] + rv[1];

        // --- pack P^T fragments (cvt_pk + permlane32_swap) and PV MFMA
        __builtin_amdgcn_s_setprio(1);
        #pragma unroll
        for (int kc = 0; kc < 4; ++kc){
            const int iA = 2*kc, iB = 2*kc + 1;
            u32 wA0 = cvtpk(PSEL(iA,0), PSEL(iA,1));
            u32 wA1 = cvtpk(PSEL(iA,2), PSEL(iA,3));
            u32 wB0 = cvtpk(PSEL(iB,0), PSEL(iB,1));
            u32 wB1 = cvtpk(PSEL(iB,2), PSEL(iB,3));
            i32x4 pw;
#if HAVE_PLS
            {
                auto r02 = __builtin_amdgcn_permlane32_swap((int)wA0, (int)wB0, false, false);
                auto r13 = __builtin_amdgcn_permlane32_swap((int)wA1, (int)wB1, false, false);
                pw[0] = r02[0]; pw[1] = r13[0]; pw[2] = r02[1]; pw[3] = r13[1];
            }
#else
            {
                u32 s0v = h ? wA0 : wB0, s1v = h ? wA1 : wB1;
                u32 g0 = (u32)__shfl_xor((int)s0v, 32);
                u32 g1 = (u32)__shfl_xor((int)s1v, 32);
                pw[0] = (int)(h ? g0 : wA0);
                pw[1] = (int)(h ? g1 : wA1);
                pw[2] = (int)(h ? wB0 : g0);
                pw[3] = (int)(h ? wB1 : g1);
            }
#endif
            bf16x8 pb = *(bf16x8*)&pw;
            bf16x8 va  = *(const bf16x8*)&Vt[c][voff0[kc]];
            bf16x8 vb2 = *(const bf16x8*)&Vt[c][voff1[kc]];
            ot0 = __builtin_amdgcn_mfma_f32_32x32x16_bf16(va,  pb, ot0, 0, 0, 0);
            ot1 = __builtin_amdgcn_mfma_f32_32x32x16_bf16(vb2, pb, ot1, 0, 0, 0);
        }
        __builtin_amdgcn_s_setprio(0);

        if (more) WRITEV(c ^ 1);   // compiler inserts the vmcnt wait for v0..v3
        __syncthreads();           // one barrier per tile: buf c^1 ready
    }

    // --- combine lane-halves, normalize, store (optional fused add)
    ll += __shfl_xor(ll, 32);
    float inv = 1.0f / ll;
    #pragma unroll
    for (int rg = 0; rg < 4; ++rg){
        int d0 = 8*rg + 4*h;
        float r0 = ot0[4*rg+0]*inv, r1 = ot0[4*rg+1]*inv, r2 = ot0[4*rg+2]*inv, r3 = ot0[4*rg+3]*inv;
        float x0 = ot1[4*rg+0]*inv, x1 = ot1[4*rg+1]*inv, x2 = ot1[4*rg+2]*inv, x3 = ot1[4*rg+3]*inv;
        if (FUSE){
            u64 ga = *(const u64*)&ADD[hb + (size_t)qrow * Dn + d0];
            u64 gb = *(const u64*)&ADD[hb + (size_t)qrow * Dn + 32 + d0];
            r0 += b2f((u16)ga);         r1 += b2f((u16)(ga >> 16));
            r2 += b2f((u16)(ga >> 32)); r3 += b2f((u16)(ga >> 48));
            x0 += b2f((u16)gb);         x1 += b2f((u16)(gb >> 16));
            x2 += b2f((u16)(gb >> 32)); x3 += b2f((u16)(gb >> 48));
        }
        *(u64*)&O[hb + (size_t)qrow * Dn + d0]      = (u64)cvtpk(r0, r1) | ((u64)cvtpk(r2, r3) << 32);
        *(u64*)&O[hb + (size_t)qrow * Dn + 32 + d0] = (u64)cvtpk(x0, x1) | ((u64)cvtpk(x2, x3) << 32);
    }
}

// ---------------------------------------------------------------------------
// Orchestration. glb_ctx + plb_ctx = glb_probs @ (gv + plb_probs @ pv).
// ---------------------------------------------------------------------------
extern "C" void kernel_launch(void* const* d_in, const int* in_sizes, int n_in,
                              void* d_out, int out_size, void* d_ws, size_t ws_size,
                              hipStream_t stream)
{
    (void)in_sizes; (void)n_in; (void)out_size; (void)ws_size;

    const float* gf  = (const float*)d_in[0];
    const float* lf  = (const float*)d_in[1];
    const float* tf  = (const float*)d_in[2];
    const float* bl1 = (const float*)d_in[4];
    const float* bl2 = (const float*)d_in[6];
    const float* bg  = (const float*)d_in[8];
    const float* bgq = (const float*)d_in[10];
    const float* bgk = (const float*)d_in[12];
    const float* bgv = (const float*)d_in[14];
    const float* bpq = (const float*)d_in[16];
    const float* bpk = (const float*)d_in[18];
    const float* bpv = (const float*)d_in[20];
    const float* bd  = (const float*)d_in[22];
    const float* bm1 = (const float*)d_in[24];
    const float* bm2 = (const float*)d_in[26];
    const float* bml = (const float*)d_in[28];

    const float C1 = 0.18033688011112042f;     // log2(e)/8, folded into pq/gq

    u16* ws = (u16*)d_ws;
    const size_t U = (size_t)Mn * Dn;          // 4,194,304 elems (8 MiB bf16)
    u16* S[9];
    for (int i = 0; i < 9; ++i) S[i] = ws + (size_t)i * U;
    u16* wtb = ws + 9 * U;

    const int sq = 65536;
    u16* Wl1t = wtb + 0*sq;  u16* Wl2t = wtb + 1*sq;  u16* Wgt  = wtb + 2*sq;
    u16* Wgqt = wtb + 3*sq;  u16* Wgkt = wtb + 4*sq;  u16* Wgvt = wtb + 5*sq;
    u16* Wpqt = wtb + 6*sq;  u16* Wpkt = wtb + 7*sq;  u16* Wpvt = wtb + 8*sq;
    u16* Wdt  = wtb + 9*sq;  u16* Wmlt = wtb + 10*sq;
    u16* Wm1t = wtb + 720896;              // [1024][256]
    u16* Wm2t = wtb + 720896 + 262144;     // [256][1024]

    // --- prep: input cvt + weight transpose, one launch
    WtArgs wa;
    const int srcidx[13] = {3,5,7,9,11,13,15,17,19,21,27,23,25};
    for (int i = 0; i < 13; ++i){
        wa.src[i] = (const float*)d_in[srcidx[i]];
        wa.kdim[i] = 256; wa.ndim[i] = 256;
        wa.dstoff[i] = i * sq;
    }
    wa.kdim[11] = 256;  wa.ndim[11] = 1024; wa.dstoff[11] = 720896;  // Wm1
    wa.kdim[12] = 1024; wa.ndim[12] = 256;  wa.dstoff[12] = 983040;  // Wm2
    int acc_t = 0;
    for (int i = 0; i < 13; ++i){
        wa.t0[i] = acc_t;
        acc_t += (wa.ndim[i] >> 5) * (wa.kdim[i] >> 5);
    }
    prep_k<<<dim3(6144 + acc_t), 256, 0, stream>>>(lf, gf, tf, S[0], S[1], S[2], wa, wtb);

    auto GN = [&](const Grp& g, int ng, int N, int K, int act, int of32){
        dim3 gr(N / 128, Mn / 64, ng);
        if (act)        gemm_k<1,0><<<gr, 256, 0, stream>>>(g, N, K);
        else if (of32)  gemm_k<0,1><<<gr, 256, 0, stream>>>(g, N, K);
        else            gemm_k<0,0><<<gr, 256, 0, stream>>>(g, N, K);
    };
    auto G1 = [&](const u16* A, const u16* Wt_, const float* b, void* C, int N, int K,
                  float sc, int act, int of32){
        Grp g{};
        g.A[0] = A; g.Wt[0] = Wt_; g.bias[0] = b; g.C[0] = C; g.scale[0] = sc;
        GN(g, 1, N, K, act, of32);
    };

    // --- level-1 projections (5 independent GEMMs, one grouped launch)
    {
        Grp g{};
        g.A[0] = S[0]; g.Wt[0] = Wl1t; g.bias[0] = bl1; g.C[0] = S[3]; g.scale[0] = 1.f; // dup_local
        g.A[1] = S[0]; g.Wt[1] = Wl2t; g.bias[1] = bl2; g.C[1] = S[4]; g.scale[1] = 1.f; // local
        g.A[2] = S[1]; g.Wt[2] = Wgt;  g.bias[2] = bg;  g.C[2] = S[5]; g.scale[2] = 1.f; // glob
        g.A[3] = S[2]; g.Wt[3] = Wpkt; g.bias[3] = bpk; g.C[3] = S[7]; g.scale[3] = 1.f; // pk
        g.A[4] = S[2]; g.Wt[4] = Wpvt; g.bias[4] = bpv; g.C[4] = S[8]; g.scale[4] = 1.f; // pv
        GN(g, 5, 256, 256, 0, 0);
    }
    // --- level-2 projections (4 GEMMs; q-projections pre-scaled by C1)
    {
        Grp g{};
        g.A[0] = S[3]; g.Wt[0] = Wpqt; g.bias[0] = bpq; g.C[0] = S[6]; g.scale[0] = C1;  // pq~
        g.A[1] = S[5]; g.Wt[1] = Wgqt; g.bias[1] = bgq; g.C[1] = S[0]; g.scale[1] = C1;  // gq~
        g.A[2] = S[4]; g.Wt[2] = Wgkt; g.bias[2] = bgk; g.C[2] = S[1]; g.scale[2] = 1.f; // gk
        g.A[3] = S[4]; g.Wt[3] = Wgvt; g.bias[3] = bgv; g.C[3] = S[2]; g.scale[3] = 1.f; // gv
        GN(g, 4, 256, 256, 0, 0);
    }

    // --- attention: vsum = attn(pq,pk,pv) + gv ; ctx = attn(gq,gk,vsum)
    attn_k<1><<<dim3(512), 256, 0, stream>>>(S[6], S[7], S[8], S[3], S[2]);
    attn_k<0><<<dim3(512), 256, 0, stream>>>(S[0], S[1], S[3], S[4], nullptr);

    // --- output projection + MLP
    G1(S[4], Wdt,  bd,  S[5], 256,  256,  1.f, 0, 0);  // out1
    G1(S[5], Wm1t, bm1, S[0], 1024, 256,  1.f, 1, 0);  // hid = gelu(...), spans S0..S3
    G1(S[0], Wm2t, bm2, S[6], 256,  1024, 1.f, 0, 0);  // out2
    G1(S[6], Wmlt, bml, d_out, 256, 256,  1.f, 0, 1);  // final (fp32 out)
}

// Round 6
// 225.757 us; speedup vs baseline: 1.0948x; 1.0948x over previous
//
#include <hip/hip_runtime.h>
#include <math.h>

#define Bn 8
#define Sn 2048
#define Dn 256
#define Hn 4
#define DHn 64
#define Mn (Bn*Sn)   // 16384 rows

typedef short bf16x8 __attribute__((ext_vector_type(8)));
typedef float f32x2  __attribute__((ext_vector_type(2)));
typedef float f32x4  __attribute__((ext_vector_type(4)));
typedef float f32x16 __attribute__((ext_vector_type(16)));
typedef int   i32x4  __attribute__((ext_vector_type(4)));
typedef unsigned short u16;
typedef unsigned int   u32;
typedef unsigned long long u64;

#if defined(__has_builtin)
#if __has_builtin(__builtin_amdgcn_global_load_lds)
#define HAVE_GLL 1
#endif
#if __has_builtin(__builtin_amdgcn_permlane32_swap)
#define HAVE_PLS 1
#endif
#endif
#ifndef HAVE_GLL
#define HAVE_GLL 0
#endif
#ifndef HAVE_PLS
#define HAVE_PLS 0
#endif

// ---------------------------------------------------------------------------
// helpers
// ---------------------------------------------------------------------------
__device__ __forceinline__ u16 f2b(float f){
    u32 u = __float_as_uint(f);
    u32 r = (u + 0x7fffu + ((u >> 16) & 1u)) >> 16;
    return (u16)r;
}
__device__ __forceinline__ float b2f(u16 h){ return __uint_as_float(((u32)h) << 16); }
__device__ __forceinline__ u32 cvtpk(float lo, float hi){
    u32 r;
    asm("v_cvt_pk_bf16_f32 %0, %1, %2" : "=v"(r) : "v"(lo), "v"(hi));
    return r;
}

// gelu(x) = x - x / (exp2(K1*x + K2*x^3) + 1)   [tanh form, exp2 domain]
__device__ __forceinline__ float gelu_f(float x){
    const float K1 = 2.3021143113f;      // 2*log2(e)*sqrt(2/pi)
    const float K2 = 0.1029390163f;      // K1 * 0.044715
    float x2 = x * x;
    float arg = fmaf(x2 * x, K2, x * K1);
    float e = exp2f(arg);
    float r = __builtin_amdgcn_rcpf(e + 1.0f);
    return x - x * r;
}

// ---------------------------------------------------------------------------
// prep: input cvt (blocks 0..6143) + weight convert (transpose or row-major)
// ---------------------------------------------------------------------------
struct WtArgs {
    const float* src[13];
    int kdim[13], ndim[13], dstoff[13], t0[13], rm[13];
};

__global__ __launch_bounds__(256) void prep_k(const float* __restrict__ lf, const float* __restrict__ gf,
                                              const float* __restrict__ tf,
                                              u16* __restrict__ o0, u16* __restrict__ o1, u16* __restrict__ o2,
                                              WtArgs a, u16* __restrict__ dst)
{
    __shared__ float tile[32][33];
    int bx = blockIdx.x;
    if (bx < 6144){
        int part = bx >> 11, blk = bx & 2047;
        const float* s = (part == 0) ? lf : (part == 1) ? gf : tf;
        u16* d = (part == 0) ? o0 : (part == 1) ? o1 : o2;
        size_t base = ((size_t)blk * 256 + threadIdx.x) * 8;
        float4 v0 = *(const float4*)(s + base);
        float4 v1 = *(const float4*)(s + base + 4);
        i32x4 o;
        o[0] = (int)cvtpk(v0.x, v0.y); o[1] = (int)cvtpk(v0.z, v0.w);
        o[2] = (int)cvtpk(v1.x, v1.y); o[3] = (int)cvtpk(v1.z, v1.w);
        *(i32x4*)(d + base) = o;
        return;
    }
    int tb = bx - 6144;
    int wi = 0;
    #pragma unroll
    for (int i = 1; i < 13; ++i) if (tb >= a.t0[i]) wi = i;
    int tt = tb - a.t0[wi];
    int N = a.ndim[wi], K = a.kdim[wi];
    int ntn = N >> 5;
    int tn = tt % ntn, tk = tt / ntn;
    int n0 = tn * 32, k0 = tk * 32;
    const float* src = a.src[wi];
    u16* out = dst + a.dstoff[wi];
    int r = threadIdx.x >> 5, c = threadIdx.x & 31;
    if (a.rm[wi]){
        // row-major bf16 copy (for mini-GEMM Wt operand)
        #pragma unroll
        for (int rr = 0; rr < 4; ++rr){
            size_t idx = (size_t)(k0 + r*4 + rr) * N + n0 + c;
            out[idx] = f2b(src[idx]);
        }
        return;
    }
    #pragma unroll
    for (int rr = 0; rr < 4; ++rr)
        tile[r*4+rr][c] = src[(size_t)(k0 + r*4 + rr) * N + n0 + c];
    __syncthreads();
    #pragma unroll
    for (int rr = 0; rr < 4; ++rr)
        out[(size_t)(n0 + r*4 + rr) * K + k0 + c] = f2b(tile[c][r*4+rr]);
}

// ---------------------------------------------------------------------------
// bias combine: bc = b1 @ W2 + b2 (4 pairs) + a zero f32 vector
// ---------------------------------------------------------------------------
__global__ __launch_bounds__(256) void bcomb_k(const float* __restrict__ W2a, const float* __restrict__ W2b,
                                               const float* __restrict__ W2c, const float* __restrict__ W2d,
                                               const float* __restrict__ b1a, const float* __restrict__ b1b,
                                               const float* __restrict__ b1c, const float* __restrict__ b1d,
                                               const float* __restrict__ b2a, const float* __restrict__ b2b,
                                               const float* __restrict__ b2c, const float* __restrict__ b2d,
                                               float* __restrict__ fb)
{
    int p = blockIdx.x, a = threadIdx.x;
    const float* W2 = (p==0)?W2a:(p==1)?W2b:(p==2)?W2c:W2d;
    const float* b1 = (p==0)?b1a:(p==1)?b1b:(p==2)?b1c:b1d;
    const float* b2 = (p==0)?b2a:(p==1)?b2b:(p==2)?b2c:b2d;
    float s = b2[a];
    for (int j = 0; j < 256; ++j) s = fmaf(b1[j], W2[(size_t)j*256 + a], s);
    fb[p*256 + a] = s;
    if (p == 0) fb[1024 + a] = 0.f;
}

// ---------------------------------------------------------------------------
// GEMM (grouped): C = act((A @ W + bias) * scale). A bf16 [M,K], Wt bf16 [N,K].
// 64x128 tile, BK=32, 4 waves, 2-phase dbuf LDS, counted vmcnt(3), GLL w16.
// Generalized XCD-chunked swizzle (gx, gy pow2; total%8==0).
// ---------------------------------------------------------------------------
struct Grp {
    const u16* A[6];
    const u16* Wt[6];
    const float* bias[6];
    void* C[6];
    float scale[6];
};

template<int ACT, int OUTF32>
__global__ __launch_bounds__(256, 4) void gemm_k(Grp g, int N, int K)
{
    const u32 gx = gridDim.x, gy = gridDim.y;
    const u32 lgx = (u32)__builtin_ctz(gx);
    const u32 lgy = (u32)__builtin_ctz(gy);
    const u32 total = gx * gy * gridDim.z;
    const u32 lid = (blockIdx.z * gy + blockIdx.y) * gx + blockIdx.x;
    const u32 nl = (lid & 7) * (total >> 3) + (lid >> 3);
    const u32 bz = nl >> (lgx + lgy);
    const u32 by = (nl >> lgx) & (gy - 1);
    const u32 bx = nl & (gx - 1);

    const u16* __restrict__ A   = g.A[bz];
    const u16* __restrict__ Wt  = g.Wt[bz];
    const float* __restrict__ bias = g.bias[bz];
    void* __restrict__ Cv = g.C[bz];
    const float scale = g.scale[bz];

    __shared__ u16 sm[2][6144];           // per buf: A tile [64][32] @0, B tile [128][32] @2048
    const int tid = threadIdx.x;
    const int w = tid >> 6, lane = tid & 63;
    const int l15 = lane & 15, l4 = lane >> 4;
    const int wr = w & 1, wc = w >> 1;
    const int bm = by << 6, bn = bx << 7;
    const int xq = l4 ^ ((lane >> 1) & 3);    // read-side swizzle

    f32x4 acc[4][2];
    #pragma unroll
    for (int nf = 0; nf < 4; ++nf)
        #pragma unroll
        for (int mf = 0; mf < 2; ++mf){
            acc[nf][mf][0]=0.f; acc[nf][mf][1]=0.f; acc[nf][mf][2]=0.f; acc[nf][mf][3]=0.f;
        }

    auto STAGE = [&](int buf, int kt){
        #pragma unroll
        for (int j = 0; j < 3; ++j){
            int ch = w*192 + j*64 + lane;     // chunk 0..767 (16B units)
            int isB = ch >= 256;
            int cc  = isB ? ch - 256 : ch;
            int row = cc >> 2, q = cc & 3;
            int qs  = q ^ ((row >> 1) & 3);   // source pre-swizzle
            const u16* src = isB ? (Wt + (size_t)(bn + row) * K + kt + qs*8)
                                 : (A  + (size_t)(bm + row) * K + kt + qs*8);
#if HAVE_GLL
            u16* lb = &sm[buf][(size_t)(w*192 + j*64) * 8];
            __builtin_amdgcn_global_load_lds((const __attribute__((address_space(1))) void*)src,
                                             (__attribute__((address_space(3))) void*)lb, 16, 0, 0);
#else
            *(i32x4*)&sm[buf][(size_t)ch * 8] = *(const i32x4*)src;
#endif
        }
    };

    STAGE(0, 0);
    const int nk = K >> 5;
    for (int t = 0; t < nk; ++t){
        const int cur = t & 1;
        if (t + 1 < nk){
            STAGE(cur ^ 1, (t + 1) << 5);
#if HAVE_GLL
            asm volatile("s_waitcnt vmcnt(3)" ::: "memory");
#endif
        } else {
#if HAVE_GLL
            asm volatile("s_waitcnt vmcnt(0)" ::: "memory");
#endif
        }
        __builtin_amdgcn_s_barrier();
        asm volatile("" ::: "memory");

        const u16* As = sm[cur];
        const u16* Bs = sm[cur] + 2048;
        bf16x8 wf[4], af[2];
        #pragma unroll
        for (int nf = 0; nf < 4; ++nf)
            wf[nf] = *(const bf16x8*)(Bs + (size_t)(wc*64 + nf*16 + l15) * 32 + xq*8);
        #pragma unroll
        for (int mf = 0; mf < 2; ++mf)
            af[mf] = *(const bf16x8*)(As + (size_t)(wr*32 + mf*16 + l15) * 32 + xq*8);
        __builtin_amdgcn_s_setprio(1);
        #pragma unroll
        for (int nf = 0; nf < 4; ++nf)
            #pragma unroll
            for (int mf = 0; mf < 2; ++mf)
                acc[nf][mf] = __builtin_amdgcn_mfma_f32_16x16x32_bf16(wf[nf], af[mf], acc[nf][mf], 0, 0, 0);
        __builtin_amdgcn_s_setprio(0);

        asm volatile("" ::: "memory");
        __builtin_amdgcn_s_barrier();
    }

    // epilogue: D[n][m]: n = bn + wc*64 + nf*16 + l4*4 + r, m = bm + wr*32 + mf*16 + l15
    #pragma unroll
    for (int nf = 0; nf < 4; ++nf){
        const int n0 = bn + wc*64 + nf*16 + l4*4;
        float4 b4 = *(const float4*)(bias + n0);
        #pragma unroll
        for (int mf = 0; mf < 2; ++mf){
            const int m = bm + wr*32 + mf*16 + l15;
            float r0 = (acc[nf][mf][0] + b4.x) * scale;
            float r1 = (acc[nf][mf][1] + b4.y) * scale;
            float r2 = (acc[nf][mf][2] + b4.z) * scale;
            float r3 = (acc[nf][mf][3] + b4.w) * scale;
            if (ACT){ r0 = gelu_f(r0); r1 = gelu_f(r1); r2 = gelu_f(r2); r3 = gelu_f(r3); }
            if (OUTF32){
                float4 o; o.x = r0; o.y = r1; o.z = r2; o.w = r3;
                *(float4*)((float*)Cv + (size_t)m * N + n0) = o;
            } else {
                u64 p = (u64)cvtpk(r0, r1) | ((u64)cvtpk(r2, r3) << 32);
                *(u64*)((u16*)Cv + (size_t)m * N + n0) = p;
            }
        }
    }
}

// ---------------------------------------------------------------------------
// bf16 MFMA flash attention: double-buffered [64][72]-padded K and V^T LDS,
// reg-staged (T14 issue-early/write-late), ONE barrier per tile.
// Q pre-scaled by log2(e)/8 in producer GEMM; fixed m=0 softmax (exact here).
// XCD-chunked 1D block swizzle.
// ---------------------------------------------------------------------------
#define PSEL(idx, mm) ((((idx) >> 2) == 0) ? pp0[(4*((idx)&3)+(mm))>>1][(4*((idx)&3)+(mm))&1] \
                                           : pp1[(4*((idx)&3)+(mm))>>1][(4*((idx)&3)+(mm))&1])

template<int FUSE>
__global__ __launch_bounds__(256, 2) void attn_k(const u16* __restrict__ Q, const u16* __restrict__ Kp,
                                                 const u16* __restrict__ Vp, u16* __restrict__ O,
                                                 const u16* __restrict__ ADD)
{
    __shared__ u16 Kl[2][4608];          // [buf][64*72], padded rows
    __shared__ u16 Vt[2][4608];          // [buf][d*72 + k], padded rows

    const int tid = threadIdx.x;
    const int w = tid >> 6, lane = tid & 63;
    const int c31 = lane & 31, h = lane >> 5;

    // ---- XCD-chunked swizzle: 512 blocks -> each XCD owns 4 heads x 16 q-blocks
    const int lid = blockIdx.x;
    const int nl = (lid & 7) * 64 + (lid >> 3);
    const int bh = nl >> 4;                          // b*H + h
    const int qb = (nl & 15) << 7;
    const size_t hb = (size_t)(bh >> 2) * Sn * Dn + (size_t)(bh & 3) * DHn;
    const int qrow = qb + w*32 + c31;

    bf16x8 qf[4];
    #pragma unroll
    for (int kc = 0; kc < 4; ++kc)
        qf[kc] = *(const bf16x8*)(Q + hb + (size_t)qrow * Dn + kc*16 + h*8);

    f32x16 ot0, ot1;
    #pragma unroll
    for (int r = 0; r < 16; ++r){ ot0[r] = 0.f; ot1[r] = 0.f; }
    float ll = 0.f;

    // loop-invariant LDS read offsets (u16 units), [72]-padded rows
    int koff0[4], koff1[4], voff0[4], voff1[4];
    #pragma unroll
    for (int kc = 0; kc < 4; ++kc){
        koff0[kc] = c31*72        + kc*16 + h*8;
        koff1[kc] = (32 + c31)*72 + kc*16 + h*8;
        voff0[kc] = koff0[kc];
        voff1[kc] = koff1[kc];
    }

    const int krow = tid >> 2, kq = tid & 3;              // K: 2x16B/thread (full row)
    const int vk0 = (tid & 15) * 4, vd0 = (tid >> 4) * 4; // V^T: 4x4 block/thread
    const u32 SEL_LO = 0x05040100u, SEL_HI = 0x07060302u;

    i32x4 kr0, kr1;
    u64 v0, v1, v2, v3;
    auto LOADKV = [&](int kt2){
        const u16* kb = Kp + hb + (size_t)(kt2 + krow) * Dn + kq*8;
        kr0 = *(const i32x4*)kb;
        kr1 = *(const i32x4*)(kb + 32);
        const u16* vb = Vp + hb + (size_t)(kt2 + vk0) * Dn + vd0;
        v0 = *(const u64*)(vb);
        v1 = *(const u64*)(vb + Dn);
        v2 = *(const u64*)(vb + 2*Dn);
        v3 = *(const u64*)(vb + 3*Dn);
    };
    auto WRITEKV = [&](int buf){
        *(i32x4*)&Kl[buf][(size_t)krow*72 + kq*8]      = kr0;
        *(i32x4*)&Kl[buf][(size_t)krow*72 + kq*8 + 32] = kr1;
        u32 a0 = (u32)v0, a1 = (u32)v1, a2 = (u32)v2, a3 = (u32)v3;
        u32 b0 = (u32)(v0 >> 32), b1 = (u32)(v1 >> 32), b2 = (u32)(v2 >> 32), b3 = (u32)(v3 >> 32);
        u64 wd0 = (u64)__builtin_amdgcn_perm(a1, a0, SEL_LO) | ((u64)__builtin_amdgcn_perm(a3, a2, SEL_LO) << 32);
        u64 wd1 = (u64)__builtin_amdgcn_perm(a1, a0, SEL_HI) | ((u64)__builtin_amdgcn_perm(a3, a2, SEL_HI) << 32);
        u64 wd2 = (u64)__builtin_amdgcn_perm(b1, b0, SEL_LO) | ((u64)__builtin_amdgcn_perm(b3, b2, SEL_LO) << 32);
        u64 wd3 = (u64)__builtin_amdgcn_perm(b1, b0, SEL_HI) | ((u64)__builtin_amdgcn_perm(b3, b2, SEL_HI) << 32);
        *(u64*)&Vt[buf][(size_t)(vd0 + 0)*72 + vk0] = wd0;
        *(u64*)&Vt[buf][(size_t)(vd0 + 1)*72 + vk0] = wd1;
        *(u64*)&Vt[buf][(size_t)(vd0 + 2)*72 + vk0] = wd2;
        *(u64*)&Vt[buf][(size_t)(vd0 + 3)*72 + vk0] = wd3;
    };

    // prologue
    LOADKV(0);
    WRITEKV(0);
    __syncthreads();

    #pragma unroll 2
    for (int t = 0; t < 32; ++t){
        const int c = t & 1;
        const bool more = (t < 31);
        if (more) LOADKV((t + 1) << 6);      // T14: issue early, full tile of cover

        // --- S^T = K @ Q^T  (per lane: 32 pre-scaled scores for q = c31)
        f32x16 s0, s1;
        #pragma unroll
        for (int r = 0; r < 16; ++r){ s0[r] = 0.f; s1[r] = 0.f; }
        __builtin_amdgcn_s_setprio(1);
        #pragma unroll
        for (int kc = 0; kc < 4; ++kc){
            bf16x8 k0 = *(const bf16x8*)&Kl[c][koff0[kc]];
            bf16x8 k1 = *(const bf16x8*)&Kl[c][koff1[kc]];
            s0 = __builtin_amdgcn_mfma_f32_32x32x16_bf16(k0, qf[kc], s0, 0, 0, 0);
            s1 = __builtin_amdgcn_mfma_f32_32x32x16_bf16(k1, qf[kc], s1, 0, 0, 0);
        }
        __builtin_amdgcn_s_setprio(0);

        // --- softmax numerator, fixed m=0: p = exp2(s); packed-pair sums
        f32x2 pp0[8], pp1[8];
        f32x2 rv = {0.f, 0.f};
        #pragma unroll
        for (int r = 0; r < 8; ++r){
            pp0[r][0] = exp2f(s0[2*r]); pp0[r][1] = exp2f(s0[2*r+1]);
            pp1[r][0] = exp2f(s1[2*r]); pp1[r][1] = exp2f(s1[2*r+1]);
            rv += pp0[r];
            rv += pp1[r];
        }
        ll += rv[0] + rv[1];

        // --- pack P^T fragments (cvt_pk + permlane32_swap) and PV MFMA
        __builtin_amdgcn_s_setprio(1);
        #pragma unroll
        for (int kc = 0; kc < 4; ++kc){
            const int iA = 2*kc, iB = 2*kc + 1;
            u32 wA0 = cvtpk(PSEL(iA,0), PSEL(iA,1));
            u32 wA1 = cvtpk(PSEL(iA,2), PSEL(iA,3));
            u32 wB0 = cvtpk(PSEL(iB,0), PSEL(iB,1));
            u32 wB1 = cvtpk(PSEL(iB,2), PSEL(iB,3));
            i32x4 pw;
#if HAVE_PLS
            {
                auto r02 = __builtin_amdgcn_permlane32_swap((int)wA0, (int)wB0, false, false);
                auto r13 = __builtin_amdgcn_permlane32_swap((int)wA1, (int)wB1, false, false);
                pw[0] = r02[0]; pw[1] = r13[0]; pw[2] = r02[1]; pw[3] = r13[1];
            }
#else
            {
                u32 s0v = h ? wA0 : wB0, s1v = h ? wA1 : wB1;
                u32 g0 = (u32)__shfl_xor((int)s0v, 32);
                u32 g1 = (u32)__shfl_xor((int)s1v, 32);
                pw[0] = (int)(h ? g0 : wA0);
                pw[1] = (int)(h ? g1 : wA1);
                pw[2] = (int)(h ? wB0 : g0);
                pw[3] = (int)(h ? wB1 : g1);
            }
#endif
            bf16x8 pb = *(bf16x8*)&pw;
            bf16x8 va  = *(const bf16x8*)&Vt[c][voff0[kc]];
            bf16x8 vb2 = *(const bf16x8*)&Vt[c][voff1[kc]];
            ot0 = __builtin_amdgcn_mfma_f32_32x32x16_bf16(va,  pb, ot0, 0, 0, 0);
            ot1 = __builtin_amdgcn_mfma_f32_32x32x16_bf16(vb2, pb, ot1, 0, 0, 0);
        }
        __builtin_amdgcn_s_setprio(0);

        if (more) WRITEKV(c ^ 1);   // write-late; compiler waits vmcnt on the loads
        __syncthreads();            // one barrier per tile
    }

    // --- combine lane-halves, normalize, store (optional fused add)
    ll += __shfl_xor(ll, 32);
    float inv = 1.0f / ll;
    #pragma unroll
    for (int rg = 0; rg < 4; ++rg){
        int d0 = 8*rg + 4*h;
        float r0 = ot0[4*rg+0]*inv, r1 = ot0[4*rg+1]*inv, r2 = ot0[4*rg+2]*inv, r3 = ot0[4*rg+3]*inv;
        float x0 = ot1[4*rg+0]*inv, x1 = ot1[4*rg+1]*inv, x2 = ot1[4*rg+2]*inv, x3 = ot1[4*rg+3]*inv;
        if (FUSE){
            u64 ga = *(const u64*)&ADD[hb + (size_t)qrow * Dn + d0];
            u64 gb = *(const u64*)&ADD[hb + (size_t)qrow * Dn + 32 + d0];
            r0 += b2f((u16)ga);         r1 += b2f((u16)(ga >> 16));
            r2 += b2f((u16)(ga >> 32)); r3 += b2f((u16)(ga >> 48));
            x0 += b2f((u16)gb);         x1 += b2f((u16)(gb >> 16));
            x2 += b2f((u16)(gb >> 32)); x3 += b2f((u16)(gb >> 48));
        }
        *(u64*)&O[hb + (size_t)qrow * Dn + d0]      = (u64)cvtpk(r0, r1) | ((u64)cvtpk(r2, r3) << 32);
        *(u64*)&O[hb + (size_t)qrow * Dn + 32 + d0] = (u64)cvtpk(x0, x1) | ((u64)cvtpk(x2, x3) << 32);
    }
}

// ---------------------------------------------------------------------------
// Orchestration.
//   glb_ctx + plb_ctx = glb_probs @ (gv + plb_probs @ pv)       [attn fold]
//   pq = lf@(Wl1@Wpq)+bc,  gq = gf@(Wg@Wgq)+bc,
//   gk = lf@(Wl2@Wgk)+bc,  gv = lf@(Wl2@Wgv)+bc                 [weight fold]
// ---------------------------------------------------------------------------
extern "C" void kernel_launch(void* const* d_in, const int* in_sizes, int n_in,
                              void* d_out, int out_size, void* d_ws, size_t ws_size,
                              hipStream_t stream)
{
    (void)in_sizes; (void)n_in; (void)out_size; (void)ws_size;

    const float* gf  = (const float*)d_in[0];
    const float* lf  = (const float*)d_in[1];
    const float* tf  = (const float*)d_in[2];
    const float* Wl1 = (const float*)d_in[3];  const float* bl1 = (const float*)d_in[4];
    const float* Wl2 = (const float*)d_in[5];  const float* bl2 = (const float*)d_in[6];
    const float* Wg  = (const float*)d_in[7];  const float* bg  = (const float*)d_in[8];
    const float* Wgq = (const float*)d_in[9];  const float* bgq = (const float*)d_in[10];
    const float* Wgk = (const float*)d_in[11]; const float* bgk = (const float*)d_in[12];
    const float* Wgv = (const float*)d_in[13]; const float* bgv = (const float*)d_in[14];
    const float* Wpq = (const float*)d_in[15]; const float* bpq = (const float*)d_in[16];
    const float* bpk = (const float*)d_in[18];
    const float* bpv = (const float*)d_in[20];
    const float* bd  = (const float*)d_in[22];
    const float* bm1 = (const float*)d_in[24];
    const float* bm2 = (const float*)d_in[26];
    const float* bml = (const float*)d_in[28];

    const float C1 = 0.18033688011112042f;     // log2(e)/8, folded into pq/gq

    u16* ws = (u16*)d_ws;
    const size_t U = (size_t)Mn * Dn;          // 4,194,304 elems (8 MiB bf16)
    u16* S[9];
    for (int i = 0; i < 9; ++i) S[i] = ws + (size_t)i * U;
    u16* wtb = ws + 9 * U;

    const int sq = 65536;
    u16* Wpqt = wtb + 0*sq;  u16* Wgqt = wtb + 1*sq;  u16* Wgkt = wtb + 2*sq;  u16* Wgvt = wtb + 3*sq;
    u16* Wpkt = wtb + 4*sq;  u16* Wpvt = wtb + 5*sq;  u16* Wdt  = wtb + 6*sq;  u16* Wmlt = wtb + 7*sq;
    u16* Wm1t = wtb + 524288;              // [1024][256]
    u16* Wm2t = wtb + 786432;              // [256][1024]
    u16* Wl1rm = wtb + 1048576;
    u16* Wl2rm = wtb + 1114112;
    u16* Wgrm  = wtb + 1179648;
    u16* Wcpqt = wtb + 1245184;            // combined (W1@W2)^T bf16, 4x
    u16* Wcgqt = wtb + 1310720;
    u16* Wcgkt = wtb + 1376256;
    u16* Wcgvt = wtb + 1441792;
    float* fb  = (float*)(wtb + 1507328);  // 4x256 combined biases + zero[256]

    // --- prep: input cvt + weight cvt, one launch
    WtArgs wa;
    const float* wsrc[13] = {Wpq, Wgq, Wgk, Wgv, (const float*)d_in[17], (const float*)d_in[19],
                             (const float*)d_in[21], (const float*)d_in[27],
                             (const float*)d_in[23], (const float*)d_in[25], Wl1, Wl2, Wg};
    const int wdst[13] = {0, sq, 2*sq, 3*sq, 4*sq, 5*sq, 6*sq, 7*sq, 524288, 786432,
                          1048576, 1114112, 1179648};
    for (int i = 0; i < 13; ++i){
        wa.src[i] = wsrc[i];
        wa.kdim[i] = 256; wa.ndim[i] = 256;
        wa.dstoff[i] = wdst[i];
        wa.rm[i] = (i >= 10);
    }
    wa.ndim[8] = 1024;                 // Wm1 [256][1024] -> T [1024][256]
    wa.kdim[9] = 1024;                 // Wm2 [1024][256] -> T [256][1024]
    int acc_t = 0;
    for (int i = 0; i < 13; ++i){
        wa.t0[i] = acc_t;
        acc_t += (wa.ndim[i] >> 5) * (wa.kdim[i] >> 5);
    }
    prep_k<<<dim3(6144 + acc_t), 256, 0, stream>>>(lf, gf, tf, S[0], S[1], S[2], wa, wtb);

    // --- combined biases (+ zero vector)
    bcomb_k<<<dim3(4), 256, 0, stream>>>(Wpq, Wgq, Wgk, Wgv, bl1, bg, bl2, bl2,
                                         bpq, bgq, bgk, bgv, fb);

    auto GN = [&](const Grp& g, int ng, int M, int N, int K, int act, int of32){
        dim3 gr(N / 128, M / 64, ng);
        if (act)        gemm_k<1,0><<<gr, 256, 0, stream>>>(g, N, K);
        else if (of32)  gemm_k<0,1><<<gr, 256, 0, stream>>>(g, N, K);
        else            gemm_k<0,0><<<gr, 256, 0, stream>>>(g, N, K);
    };
    auto G1 = [&](const u16* A, const u16* Wt_, const float* b, void* C, int N, int K,
                  float sc, int act, int of32){
        Grp g{};
        g.A[0] = A; g.Wt[0] = Wt_; g.bias[0] = b; g.C[0] = C; g.scale[0] = sc;
        GN(g, 1, Mn, N, K, act, of32);
    };

    // --- mini grouped GEMM: Wc^T = W2^T @ W1^T  (M=256, 32 blocks)
    {
        Grp g{};
        g.A[0] = Wpqt; g.Wt[0] = Wl1rm; g.bias[0] = fb + 1024; g.C[0] = Wcpqt; g.scale[0] = 1.f;
        g.A[1] = Wgqt; g.Wt[1] = Wgrm;  g.bias[1] = fb + 1024; g.C[1] = Wcgqt; g.scale[1] = 1.f;
        g.A[2] = Wgkt; g.Wt[2] = Wl2rm; g.bias[2] = fb + 1024; g.C[2] = Wcgkt; g.scale[2] = 1.f;
        g.A[3] = Wgvt; g.Wt[3] = Wl2rm; g.bias[3] = fb + 1024; g.C[3] = Wcgvt; g.scale[3] = 1.f;
        GN(g, 4, 256, 256, 256, 0, 0);
    }

    // --- all 6 projections in ONE grouped launch (direct from raw inputs)
    {
        Grp g{};
        g.A[0] = S[0]; g.Wt[0] = Wcpqt; g.bias[0] = fb + 0;   g.C[0] = S[3]; g.scale[0] = C1;  // pq~
        g.A[1] = S[1]; g.Wt[1] = Wcgqt; g.bias[1] = fb + 256; g.C[1] = S[6]; g.scale[1] = C1;  // gq~
        g.A[2] = S[0]; g.Wt[2] = Wcgkt; g.bias[2] = fb + 512; g.C[2] = S[7]; g.scale[2] = 1.f; // gk
        g.A[3] = S[0]; g.Wt[3] = Wcgvt; g.bias[3] = fb + 768; g.C[3] = S[8]; g.scale[3] = 1.f; // gv
        g.A[4] = S[2]; g.Wt[4] = Wpkt;  g.bias[4] = bpk;      g.C[4] = S[4]; g.scale[4] = 1.f; // pk
        g.A[5] = S[2]; g.Wt[5] = Wpvt;  g.bias[5] = bpv;      g.C[5] = S[5]; g.scale[5] = 1.f; // pv
        GN(g, 6, Mn, 256, 256, 0, 0);
    }

    // --- attention: vsum = attn(pq,pk,pv) + gv ; ctx = attn(gq,gk,vsum)
    attn_k<1><<<dim3(512), 256, 0, stream>>>(S[3], S[4], S[5], S[0], S[8]);
    attn_k<0><<<dim3(512), 256, 0, stream>>>(S[6], S[7], S[0], S[1], nullptr);

    // --- output projection + MLP
    G1(S[1], Wdt,  bd,  S[2], 256,  256,  1.f, 0, 0);  // out1
    G1(S[2], Wm1t, bm1, S[3], 1024, 256,  1.f, 1, 0);  // hid = gelu(...), spans S3..S6
    G1(S[3], Wm2t, bm2, S[7], 256,  1024, 1.f, 0, 0);  // out2
    G1(S[7], Wmlt, bml, d_out, 256, 256,  1.f, 0, 1);  // final (fp32 out)
}